// Round 2
// baseline (3935.480 us; speedup 1.0000x reference)
//
#include <hip/hip_runtime.h>
#include <math.h>

// ---------------- problem constants (fixed by the reference) ----------------
#define NN 50000
#define EE 800000
#define GG 256
#define E2 (EE + NN)          // edges + self loops
constexpr float NEG_SLOPE = 0.2f;
constexpr float BN_EPS_C  = 1e-5f;

static inline int cdiv(long a, long b) { return (int)((a + b - 1) / b); }

// ---------------- small utility kernels ----------------
__global__ void k_fill(float* __restrict__ p, float v, int n) {
    int i = blockIdx.x * blockDim.x + threadIdx.x;
    if (i < n) p[i] = v;
}

__device__ __forceinline__ void atomicMaxFloat(float* addr, float val) {
    // IEEE-754 ordering trick; correct for all non-NaN values
    if (val >= 0.0f) atomicMax((int*)addr, __float_as_int(val));
    else             atomicMin((unsigned int*)addr, __float_as_uint(val));
}

// ---------------- GIN: scatter-add of h[src] into agg[dst] ----------------
// one 64-lane wave per edge, lane = feature channel
__global__ void k_scatter_add64(const float* __restrict__ h, const int* __restrict__ src,
                                const int* __restrict__ dst, float* __restrict__ agg) {
    int gt = blockIdx.x * blockDim.x + threadIdx.x;
    int e = gt >> 6, lane = gt & 63;
    if (e >= EE) return;
    int s = src[e], d = dst[e];
    atomicAdd(&agg[d * 64 + lane], h[s * 64 + lane]);
}

// ---------------- generic tiled GEMM: out = act(bn((A[+A2]) @ W + bias)) ----------------
// A: n x K, W: K x M (row-major), out: n x M.  Block = (M, 256/M).
template<int K, int M, bool SUM2, bool BN, bool RELU>
__global__ __launch_bounds__(256)
void k_mm(const float* __restrict__ A, const float* __restrict__ A2,
          const float* __restrict__ W, const float* __restrict__ bias,
          const float* __restrict__ bng, const float* __restrict__ bnb,
          const float* __restrict__ bnm, const float* __restrict__ bnv,
          float* __restrict__ out, int n) {
    constexpr int R = 256 / M;
    __shared__ float Ws[64][M];
    __shared__ float As[R][64];
    const int tx = threadIdx.x, ty = threadIdx.y;
    const int t = ty * M + tx;
    const int row0 = blockIdx.x * R;
    float acc = 0.0f;
    for (int kb = 0; kb < K; kb += 64) {
        for (int i = t; i < 64 * M; i += 256)
            Ws[i / M][i % M] = W[(kb + i / M) * M + (i % M)];
        for (int i = t; i < R * 64; i += 256) {
            int r = i / 64, c = i % 64;
            int row = row0 + r;
            float v = 0.0f;
            if (row < n) {
                v = A[(long)row * K + kb + c];
                if (SUM2) v += A2[(long)row * K + kb + c];
            }
            As[r][c] = v;
        }
        __syncthreads();
        #pragma unroll
        for (int kk = 0; kk < 64; ++kk) acc += As[ty][kk] * Ws[kk][tx];
        __syncthreads();
    }
    const int row = row0 + ty;
    if (row >= n) return;
    float v = acc + bias[tx];
    if (BN) {
        float s = bng[tx] * rsqrtf(bnv[tx] + BN_EPS_C);
        v = (v - bnm[tx]) * s + bnb[tx];
    }
    if (RELU) v = fmaxf(v, 0.0f);
    out[(long)row * M + tx] = v;
}

// ---------------- GATv2 edge pass 1: alpha + segment max ----------------
// wave per edge (incl. self loops), lane = channel within head
template<int HH, int M>
__global__ void k_gat_alpha(const float* __restrict__ xl, const float* __restrict__ xr,
                            const float* __restrict__ att, const int* __restrict__ src,
                            const int* __restrict__ dst, float* __restrict__ alpha,
                            float* __restrict__ amax) {
    int gt = blockIdx.x * blockDim.x + threadIdx.x;
    int e = gt >> 6, lane = gt & 63;
    if (e >= E2) return;
    int s, d;
    if (e < EE) { s = src[e]; d = dst[e]; } else { s = d = e - EE; }
    #pragma unroll
    for (int h = 0; h < HH; ++h) {
        float v = xl[(long)s * M + h * 64 + lane] + xr[(long)d * M + h * 64 + lane];
        v = (v > 0.0f) ? v : NEG_SLOPE * v;
        float p = v * att[h * 64 + lane];
        #pragma unroll
        for (int off = 32; off; off >>= 1) p += __shfl_xor(p, off);
        if (lane == 0) {
            alpha[(long)e * HH + h] = p;
            atomicMaxFloat(&amax[d * HH + h], p);
        }
    }
}

// ---------------- GATv2 edge pass 2: exp + denom ----------------
template<int HH>
__global__ void k_gat_exp(const int* __restrict__ dst, float* __restrict__ alpha,
                          const float* __restrict__ amax, float* __restrict__ denom) {
    int id = blockIdx.x * blockDim.x + threadIdx.x;
    if (id >= E2 * HH) return;
    int e = id / HH, h = id - e * HH;
    int d = (e < EE) ? dst[e] : e - EE;
    float ex = expf(alpha[id] - amax[d * HH + h]);
    alpha[id] = ex;
    atomicAdd(&denom[d * HH + h], ex);
}

// ---------------- GATv2 edge pass 3: weighted scatter ----------------
template<int HH, int M>
__global__ void k_gat_scatter(const float* __restrict__ xl, const int* __restrict__ src,
                              const int* __restrict__ dst, const float* __restrict__ alpha,
                              const float* __restrict__ denom, float* __restrict__ acc) {
    int gt = blockIdx.x * blockDim.x + threadIdx.x;
    int e = gt >> 6, lane = gt & 63;
    if (e >= E2) return;
    int s, d;
    if (e < EE) { s = src[e]; d = dst[e]; } else { s = d = e - EE; }
    #pragma unroll
    for (int h = 0; h < HH; ++h) {
        float a = alpha[(long)e * HH + h] / (denom[d * HH + h] + 1e-16f);
        atomicAdd(&acc[(long)d * M + h * 64 + lane],
                  xl[(long)s * M + h * 64 + lane] * a);
    }
}

// ---------------- bias + relu epilogue ----------------
__global__ void k_bias_relu(const float* __restrict__ acc, const float* __restrict__ bias,
                            float* __restrict__ out, int total, int mmask) {
    int i = blockIdx.x * blockDim.x + threadIdx.x;
    if (i >= total) return;
    out[i] = fmaxf(acc[i] + bias[i & mmask], 0.0f);
}

// ---------------- mean pool (atomics) ----------------
__global__ void k_pool(const float* __restrict__ gin, const float* __restrict__ gat,
                       const int* __restrict__ batch, float* __restrict__ pooled,
                       float* __restrict__ counts) {
    int i = blockIdx.x * blockDim.x + threadIdx.x;
    if (i >= NN * 128) return;
    int v = i >> 7, c = i & 127;
    int g = batch[v];
    float val = (c < 64) ? gin[v * 64 + c] : gat[v * 64 + (c - 64)];
    atomicAdd(&pooled[g * 128 + c], val);
    if (c == 0) atomicAdd(&counts[g], 1.0f);
}

// ---------------- graph head: rep = pooled/cnt @ Wg + bg ; logits ----------------
__global__ void k_head(const float* __restrict__ pooled, const float* __restrict__ counts,
                       const float* __restrict__ gw, const float* __restrict__ gb,
                       const float* __restrict__ cw, const float* __restrict__ cb,
                       float* __restrict__ out) {
    int g = blockIdx.x;
    int j = threadIdx.x;      // 64 threads = 1 wave
    __shared__ float prow[128];
    float cnt = fmaxf(counts[g], 1.0f);
    prow[j]      = pooled[g * 128 + j] / cnt;
    prow[j + 64] = pooled[g * 128 + 64 + j] / cnt;
    __syncthreads();
    float acc = gb[j];
    #pragma unroll
    for (int k = 0; k < 128; ++k) acc += prow[k] * gw[k * 64 + j];
    // graph_rep output: [G, 65] at offset GG (after logits)
    out[GG + g * 65 + j] = acc;
    if (j == 0) out[GG + g * 65 + 64] = 0.0f;     // lovasz stub
    float p = acc * cw[j];
    #pragma unroll
    for (int off = 32; off; off >>= 1) p += __shfl_xor(p, off);
    if (j == 0) out[g] = p + cb[0];               // cw[64]*0 contributes nothing
}

// ---------------- host launcher ----------------
extern "C" void kernel_launch(void* const* d_in, const int* in_sizes, int n_in,
                              void* d_out, int out_size, void* d_ws, size_t ws_size,
                              hipStream_t stream) {
    const float* x        = (const float*)d_in[0];
    const int*   ei       = (const int*)d_in[1];
    const int*   src      = ei;
    const int*   dst      = ei + EE;
    const int*   batch    = (const int*)d_in[2];
    const float* gin_w1   = (const float*)d_in[3];
    const float* gin_b1   = (const float*)d_in[4];
    const float* gin_bn_g = (const float*)d_in[5];
    const float* gin_bn_b = (const float*)d_in[6];
    const float* gin_bn_m = (const float*)d_in[7];
    const float* gin_bn_v = (const float*)d_in[8];
    const float* gin_w2   = (const float*)d_in[9];
    const float* gin_b2   = (const float*)d_in[10];
    const float* gat_wl[3]   = {(const float*)d_in[11], (const float*)d_in[17], (const float*)d_in[23]};
    const float* gat_bl[3]   = {(const float*)d_in[12], (const float*)d_in[18], (const float*)d_in[24]};
    const float* gat_wr[3]   = {(const float*)d_in[13], (const float*)d_in[19], (const float*)d_in[25]};
    const float* gat_br[3]   = {(const float*)d_in[14], (const float*)d_in[20], (const float*)d_in[26]};
    const float* gat_att[3]  = {(const float*)d_in[15], (const float*)d_in[21], (const float*)d_in[27]};
    const float* gat_bias[3] = {(const float*)d_in[16], (const float*)d_in[22], (const float*)d_in[28]};
    const float* graph_w  = (const float*)d_in[29];
    const float* graph_b  = (const float*)d_in[30];
    const float* clf_w    = (const float*)d_in[31];
    const float* clf_b    = (const float*)d_in[32];
    float* out = (float*)d_out;

    // ---- workspace carve-up (floats) ----
    float* ws = (float*)d_ws;
    size_t o = 0;
    auto alloc = [&](size_t n) { float* p = ws + o; o += n; return p; };
    float* gin_h   = alloc((size_t)NN * 64);
    float* gin_tmp = alloc((size_t)NN * 64);
    float* gin_agg = alloc((size_t)NN * 64);
    float* gat_h   = alloc((size_t)NN * 128);
    float* gat_xl  = alloc((size_t)NN * 128);
    float* gat_xr  = alloc((size_t)NN * 128);
    float* gat_acc = alloc((size_t)NN * 128);
    float* gat_out = alloc((size_t)NN * 64);
    float* alpha   = alloc((size_t)E2 * 2);
    float* amax    = alloc((size_t)NN * 2);
    float* denom   = alloc((size_t)NN * 2);
    float* pooled  = alloc((size_t)GG * 128);
    float* counts  = alloc((size_t)GG);
    (void)ws_size; (void)n_in; (void)in_sizes; (void)out_size;

    const int TB = 256;

    // =================== GIN encoder ===================
    const float* hin = x;
    for (int l = 0; l < 3; ++l) {
        k_fill<<<cdiv((long)NN * 64, TB), TB, 0, stream>>>(gin_agg, 0.0f, NN * 64);
        k_scatter_add64<<<cdiv((long)EE * 64, TB), TB, 0, stream>>>(hin, src, dst, gin_agg);
        k_mm<64, 64, true, true, true><<<cdiv(NN, 4), dim3(64, 4), 0, stream>>>(
            hin, gin_agg, gin_w1 + l * 4096, gin_b1 + l * 64,
            gin_bn_g + l * 64, gin_bn_b + l * 64, gin_bn_m + l * 64, gin_bn_v + l * 64,
            gin_tmp, NN);
        k_mm<64, 64, false, false, true><<<cdiv(NN, 4), dim3(64, 4), 0, stream>>>(
            gin_tmp, nullptr, gin_w2 + l * 4096, gin_b2 + l * 64,
            nullptr, nullptr, nullptr, nullptr, gin_h, NN);
        hin = gin_h;
    }

    // =================== GATv2 encoder ===================
    const float* hg = x;
    for (int l = 0; l < 3; ++l) {
        const int HH = (l == 2) ? 1 : 2;
        const int M  = HH * 64;            // output width
        // xl / xr transforms
        if (l == 0) {
            k_mm<64, 128, false, false, false><<<cdiv(NN, 2), dim3(128, 2), 0, stream>>>(
                hg, nullptr, gat_wl[l], gat_bl[l], nullptr, nullptr, nullptr, nullptr, gat_xl, NN);
            k_mm<64, 128, false, false, false><<<cdiv(NN, 2), dim3(128, 2), 0, stream>>>(
                hg, nullptr, gat_wr[l], gat_br[l], nullptr, nullptr, nullptr, nullptr, gat_xr, NN);
        } else if (l == 1) {
            k_mm<128, 128, false, false, false><<<cdiv(NN, 2), dim3(128, 2), 0, stream>>>(
                hg, nullptr, gat_wl[l], gat_bl[l], nullptr, nullptr, nullptr, nullptr, gat_xl, NN);
            k_mm<128, 128, false, false, false><<<cdiv(NN, 2), dim3(128, 2), 0, stream>>>(
                hg, nullptr, gat_wr[l], gat_br[l], nullptr, nullptr, nullptr, nullptr, gat_xr, NN);
        } else {
            k_mm<128, 64, false, false, false><<<cdiv(NN, 4), dim3(64, 4), 0, stream>>>(
                hg, nullptr, gat_wl[l], gat_bl[l], nullptr, nullptr, nullptr, nullptr, gat_xl, NN);
            k_mm<128, 64, false, false, false><<<cdiv(NN, 4), dim3(64, 4), 0, stream>>>(
                hg, nullptr, gat_wr[l], gat_br[l], nullptr, nullptr, nullptr, nullptr, gat_xr, NN);
        }
        // init segment buffers
        k_fill<<<cdiv((long)NN * HH, TB), TB, 0, stream>>>(amax, -INFINITY, NN * HH);
        k_fill<<<cdiv((long)NN * HH, TB), TB, 0, stream>>>(denom, 0.0f, NN * HH);
        k_fill<<<cdiv((long)NN * M, TB), TB, 0, stream>>>(gat_acc, 0.0f, NN * M);
        // edge passes
        if (HH == 2) {
            k_gat_alpha<2, 128><<<cdiv((long)E2 * 64, TB), TB, 0, stream>>>(
                gat_xl, gat_xr, gat_att[l], src, dst, alpha, amax);
            k_gat_exp<2><<<cdiv((long)E2 * 2, TB), TB, 0, stream>>>(dst, alpha, amax, denom);
            k_gat_scatter<2, 128><<<cdiv((long)E2 * 64, TB), TB, 0, stream>>>(
                gat_xl, src, dst, alpha, denom, gat_acc);
        } else {
            k_gat_alpha<1, 64><<<cdiv((long)E2 * 64, TB), TB, 0, stream>>>(
                gat_xl, gat_xr, gat_att[l], src, dst, alpha, amax);
            k_gat_exp<1><<<cdiv((long)E2 * 1, TB), TB, 0, stream>>>(dst, alpha, amax, denom);
            k_gat_scatter<1, 64><<<cdiv((long)E2 * 64, TB), TB, 0, stream>>>(
                gat_xl, src, dst, alpha, denom, gat_acc);
        }
        // epilogue: bias + relu
        float* hout = (l == 2) ? gat_out : gat_h;
        k_bias_relu<<<cdiv((long)NN * M, TB), TB, 0, stream>>>(gat_acc, gat_bias[l], hout, NN * M, M - 1);
        hg = hout;
    }

    // =================== pool + heads ===================
    k_fill<<<cdiv((long)GG * 129, TB), TB, 0, stream>>>(pooled, 0.0f, GG * 129); // pooled + counts contiguous
    k_pool<<<cdiv((long)NN * 128, TB), TB, 0, stream>>>(gin_h, gat_out, batch, pooled, counts);
    k_head<<<GG, 64, 0, stream>>>(pooled, counts, graph_w, graph_b, clf_w, clf_b, out);
}